// Round 3
// baseline (305.845 us; speedup 1.0000x reference)
//
#include <hip/hip_runtime.h>
#include <math.h>

// Problem constants (B=1, NHEADS=1)
#define TT   3
#define CC   64
#define HH   192
#define WW   192
#define HWW  (HH*WW)       // 36864
#define NHC  24            // H / STRIDE0_A
#define NWC  24
#define QC   1728          // T*NHC*NWC
#define SC   192           // st*WS*WS = 3*8*8
#define NPIX 49            // PS*PS
#define KK   7
#define NHF  48            // H / STRIDE0
#define NWF  48
#define QF   6912          // T*NHF*NWF

__device__ __forceinline__ int reflect(int i, int L) {
  i = i < 0 ? -i : i;
  return (i >= L) ? (2 * (L - 1) - i) : i;
}

// ---------------------------------------------------------------------------
// (T,C,H,W) -> (T,H,W,C) fp32 transpose, 64x64 (c,x) tiles per (t,y).
// ---------------------------------------------------------------------------
__global__ void transpose_tchw_thwc(const float* __restrict__ in0,
                                    const float* __restrict__ in1,
                                    float* __restrict__ out0,
                                    float* __restrict__ out1) {
  const float* in = blockIdx.y ? in1 : in0;
  float* out = blockIdx.y ? out1 : out0;
  int b = blockIdx.x;              // 0 .. T*H*(W/64)-1
  int x0 = (b % 3) * 64;
  int ty = b / 3;                  // t*H + y
  int t = ty / HH, y = ty % HH;

  __shared__ float tile[64][65];   // +1 pad
  int lx = threadIdx.x & 63;
  int lc = threadIdx.x >> 6;       // 0..3

  const float* src = in + (size_t)t * CC * HWW + (size_t)y * WW + x0;
#pragma unroll
  for (int i = 0; i < 16; ++i) {
    int c = lc + i * 4;
    tile[c][lx] = src[(size_t)c * HWW + lx];
  }
  __syncthreads();
  float* dst = out + ((size_t)(t * HH + y) * WW + x0) * CC;
#pragma unroll
  for (int i = 0; i < 16; ++i) {
    int x = lc + i * 4;
    dst[(size_t)x * CC + lx] = tile[lx][x];   // coalesced along c
  }
}

// ---------------------------------------------------------------------------
// Coarse dists, bit-exact vs the XLA chain:
//   w(s,p) = serial ascending-c FMA chain, single fp32 acc (c 0..63, carried
//            in a register across the two c-halves).
//   dist  = 49 sequential fp32 adds, p ascending (lax.scan order).
//
// v4 (same math order as v2/v3):
//  - thread = (sA = lane&31, sB = sA+32) x p in {rres + 8i}, rres = w + 4*ph
//    (ph = lane>>5). Halves qbuf broadcast reads (one per s-pair). Region
//    read for sB is region(sA) + 896 B (oi differs by 4 -> px by 56).
//  - wbuf ALIASED into region4 (never live together; extra barrier) ->
//    LDS 37632 B -> 4 blocks/CU (was 3 at 50176).
//  - staging offsets precomputed once (ct/h-invariant); next half's global
//    loads issued right after the current half's LDS write -> latency hides
//    under compute (async-stage split).
//  - region read slot distribution unchanged: 8 lanes per 16B slot (b128
//    floor); staging writes keep the conflict-free swizzled lane map.
// ---------------------------------------------------------------------------
__global__ __launch_bounds__(256, 4) void coarse_fma_kernel(
    const float* __restrict__ v0, const float* __restrict__ v1,
    float* __restrict__ dists) {
  int bid = blockIdx.x;
  int q = (bid & 7) * (QC / 8) + (bid >> 3);   // XCD swizzle, bijective
  int qt = q / (NHC * NWC);
  int r = q % (NHC * NWC);
  int qh = (r / NWC) * 8;
  int qw = (r % NWC) * 8;

  __shared__ float4 region4[8 * 196];   // [c4h][px] 25088 B; wbuf aliases
  __shared__ float4 qbuf4[16 * 49];     // [c4][p]   12544 B  (total 37632)
  float* wbuf = (float*)region4;        // [s][p] 12544 B, after compute sync

  int tid = threadIdx.x;
  int lane = tid & 63;
  int w = tid >> 6;                     // wave id 0..3
  int ph = lane >> 5;                   // p-residue half
  int sA = lane & 31;                   // owns sA and sA+32
  int oiA = sA >> 3, oj = sA & 7;
  int rres = w + 4 * ph;                // p residue mod 8, 0..7
  // p-count: rres==0 -> 7 (p=0,8,..,48), else 6.

  // Region byte offsets for sA at p = rres + 8i (sB: +896).
  int pxb[7];
#pragma unroll
  for (int i = 0; i < 7; ++i) {
    int p = rres + 8 * i;
    if (p > 48) p = 48;                 // clamped slot never used
    pxb[i] = ((oiA + p / 7) * 14 + (oj + p % 7)) * 16;
  }

  // Staging slots, ct/h-invariant. idx = tid + 256j; px in low lane bits so
  // write 16B-slots are even. sdst = -1 marks an unused slot.
  int srow[7], sdst[7];
#pragma unroll
  for (int j = 0; j < 7; ++j) {
    int idx = tid + 256 * j;
    int px = (idx & 7) | ((idx >> 6) << 3);
    int c4h = (idx >> 3) & 7;
    if (idx < 1600 && px < 196) {
      int ry = reflect(qh - 7 + px / 14, HH);
      int rx = reflect(qw - 7 + px % 14, WW);
      srow[j] = (ry * WW + rx) * CC + c4h * 4;   // float index, h adds 32
      sdst[j] = c4h * 196 + px;
    } else {
      srow[j] = 0;
      sdst[j] = -1;
    }
  }

  // Stage query patch [c4][p] float4 (write slots even over lanes).
  {
    const float* b0 = v0 + (size_t)qt * HWW * CC;
    for (int idx = tid; idx < 896; idx += 256) {
      int p = (idx & 7) | ((idx >> 7) << 3);
      int c4 = (idx >> 3) & 15;
      if (p < 49) {
        int ry = reflect(qh + p / 7 - 3, HH);
        int rx = reflect(qw + p % 7 - 3, WW);
        qbuf4[c4 * 49 + p] = *reinterpret_cast<const float4*>(
            b0 + ((size_t)ry * WW + rx) * CC + c4 * 4);
      }
    }
  }

  // Prefetch (ct=0, h=0) region half into registers.
  float4 rbuf[7];
#pragma unroll
  for (int j = 0; j < 7; ++j)
    if (sdst[j] >= 0)
      rbuf[j] = *reinterpret_cast<const float4*>(v1 + srow[j]);

  for (int ct = 0; ct < 3; ++ct) {
    float accA[7], accB[7];
#pragma unroll
    for (int i = 0; i < 7; ++i) { accA[i] = 0.f; accB[i] = 0.f; }

#pragma unroll
    for (int h = 0; h < 2; ++h) {
      __syncthreads();   // prior region4/wbuf readers done
      // Commit prefetched half to LDS.
#pragma unroll
      for (int j = 0; j < 7; ++j)
        if (sdst[j] >= 0) region4[sdst[j]] = rbuf[j];
      // Issue next half's loads (hide latency under compute below).
      if (h == 0) {
        const float* nb = v1 + (size_t)ct * HWW * CC + 32;   // (ct, h=1)
#pragma unroll
        for (int j = 0; j < 7; ++j)
          if (sdst[j] >= 0)
            rbuf[j] = *reinterpret_cast<const float4*>(nb + srow[j]);
      } else if (ct < 2) {
        const float* nb = v1 + (size_t)(ct + 1) * HWW * CC;  // (ct+1, h=0)
#pragma unroll
        for (int j = 0; j < 7; ++j)
          if (sdst[j] >= 0)
            rbuf[j] = *reinterpret_cast<const float4*>(nb + srow[j]);
      }
      __syncthreads();   // region4 half h visible

      // Continue each dot's serial chain: c = 32h .. 32h+31, ascending,
      // single register accumulator per (s,p) — bit-identical ordering.
#pragma unroll
      for (int i = 0; i < 7; ++i) {
        if (i < 6 || rres == 0) {
          int p = rres + 8 * i;
          const char* ra = reinterpret_cast<const char*>(region4) + pxb[i];
#pragma unroll
          for (int c4h = 0; c4h < 8; ++c4h) {
            float4 a = qbuf4[(h * 8 + c4h) * 49 + p];
            float4 bA = *reinterpret_cast<const float4*>(ra + c4h * 3136);
            float4 bB =
                *reinterpret_cast<const float4*>(ra + c4h * 3136 + 896);
            accA[i] = fmaf(a.x, bA.x, accA[i]);   // ascending c, fused
            accA[i] = fmaf(a.y, bA.y, accA[i]);
            accA[i] = fmaf(a.z, bA.z, accA[i]);
            accA[i] = fmaf(a.w, bA.w, accA[i]);
            accB[i] = fmaf(a.x, bB.x, accB[i]);
            accB[i] = fmaf(a.y, bB.y, accB[i]);
            accB[i] = fmaf(a.z, bB.z, accB[i]);
            accB[i] = fmaf(a.w, bB.w, accB[i]);
          }
        }
      }
    }

    __syncthreads();     // all region4 readers done -> wbuf alias writable
#pragma unroll
    for (int i = 0; i < 7; ++i) {
      if (i < 6 || rres == 0) {
        int p = rres + 8 * i;
        wbuf[sA * 49 + p] = accA[i];
        wbuf[(sA + 32) * 49 + p] = accB[i];
      }
    }
    __syncthreads();
    if (tid < 64) {
      float a = 0.f;
      const float* wr = wbuf + tid * 49;
      for (int p = 0; p < NPIX; ++p)
        a = __fadd_rn(a, wr[p]);         // scan order, fp32
      dists[(size_t)q * SC + ct * 64 + tid] = a;
    }
    // Next ct's first __syncthreads fences the reduce before region reuse.
  }
}

// ---------------------------------------------------------------------------
// Top-K (K=7): one WAVE per query. Lane owns candidates {lane, lane+64,
// lane+128}. Bit-exact vs serial strict-'>' ascending scan (ties -> lowest
// index via the cross-lane index tie-break).
// ---------------------------------------------------------------------------
__global__ __launch_bounds__(256) void topk_kernel(
    const float* __restrict__ dists, int* __restrict__ topk) {
  int q = blockIdx.x * 4 + (threadIdx.x >> 6);
  if (q >= QC) return;
  int lane = threadIdx.x & 63;
  const float* d = dists + (size_t)q * SC;
  float v[3] = {d[lane], d[lane + 64], d[lane + 128]};
  int tk = 0;                            // taken bitmask (per-lane, 3 bits)
#pragma unroll
  for (int k = 0; k < KK; ++k) {
    float bv = -INFINITY;
    int bi = 0x7fffffff;
#pragma unroll
    for (int j = 0; j < 3; ++j) {
      if (!((tk >> j) & 1) && v[j] > bv) { bv = v[j]; bi = lane + j * 64; }
    }
#pragma unroll
    for (int off = 32; off > 0; off >>= 1) {
      float ov = __shfl_xor(bv, off, 64);
      int oi = __shfl_xor(bi, off, 64);
      if (ov > bv || (ov == bv && oi < bi)) { bv = ov; bi = oi; }
    }
    if ((bi & 63) == lane) tk |= 1 << (bi >> 6);
    if (lane == 0) topk[q * KK + k] = bi;
  }
}

// ---------------------------------------------------------------------------
// Refine. One block per fine query, 448 threads = 7 waves, one wave per
// candidate k. Query patch staged once in LDS; candidate loads batched
// 7-wide for ILP. XCD swizzle for L2 locality.
// ---------------------------------------------------------------------------
__global__ __launch_bounds__(448, 7) void refine_kernel(
    const float* __restrict__ v0, const float* __restrict__ v1,
    const int* __restrict__ topk, float* __restrict__ out) {
  int bid = blockIdx.x;
  int f = (bid & 7) * (QF / 8) + (bid >> 3);   // XCD swizzle, bijective
  int ft = f / (NHF * NWF);
  int r = f % (NHF * NWF);
  int fi = r / NWF, fj = r % NWF;
  int fh = fi * 4, fw = fj * 4;
  int ci = fi >> 1, cj = fj >> 1;     // clip is a no-op here
  int dh = (fi & 1) * 4, dw = (fj & 1) * 4;
  int qlin = ft * (NHC * NWC) + ci * NWC + cj;

  int tid = threadIdx.x;
  int lane = tid & 63;
  int k = tid >> 6;                   // wave id == candidate id, 0..6

  __shared__ float qs[NPIX * CC];     // [p][c], 12544 B

  {
    const float* b0 = v0 + (size_t)ft * HWW * CC;
#pragma unroll
    for (int i = 0; i < 7; ++i) {     // 7 * 448 = 3136 = NPIX*CC exactly
      int idx = tid + i * 448;
      int p = idx >> 6, c = idx & 63;
      int ry = reflect(fh + p / 7 - 3, HH);
      int rx = reflect(fw + p % 7 - 3, WW);
      qs[idx] = b0[((size_t)ry * WW + rx) * CC + c];
    }
  }
  __syncthreads();

  int it, ih, iw;
  if (k == 0) {
    it = ft; ih = fh; iw = fw;
  } else {
    int s = topk[qlin * KK + k];
    int ti = s >> 6;                  // ct index (t0 == 0 always)
    int oi = (s >> 3) & 7, oj = s & 7;
    it = ti;
    ih = reflect(ci * 8 + oi - 4 + dh, HH);
    iw = reflect(cj * 8 + oj - 4 + dw, WW);
  }

  const float* b1 = v1 + (size_t)it * HWW * CC;
  float acc = 0.f;
#pragma unroll
  for (int pr = 0; pr < 7; ++pr) {
    int ry = reflect(ih + pr - 3, HH);
    const float* rowp = b1 + (size_t)ry * WW * CC + lane;
    float vals[7];
#pragma unroll
    for (int pc = 0; pc < 7; ++pc) {
      int rx = reflect(iw + pc - 3, WW);
      vals[pc] = rowp[(size_t)rx * CC];       // 7 independent loads in flight
    }
#pragma unroll
    for (int pc = 0; pc < 7; ++pc)
      acc = fmaf(qs[(pr * 7 + pc) * CC + lane], vals[pc], acc);
  }
#pragma unroll
  for (int off = 32; off > 0; off >>= 1)
    acc += __shfl_xor(acc, off, 64);
  if (lane == 0) {
    float* dout = out;                      // [0, QF*KK)
    float* iout = out + (size_t)QF * KK;    // [QF*KK, QF*KK*4)
    dout[(size_t)f * KK + k] = acc;
    float* ip = iout + ((size_t)f * KK + k) * 3;
    ip[0] = (float)it;
    ip[1] = (float)ih;
    ip[2] = (float)iw;
  }
}

// ---------------------------------------------------------------------------
extern "C" void kernel_launch(void* const* d_in, const int* in_sizes, int n_in,
                              void* d_out, int out_size, void* d_ws,
                              size_t ws_size, hipStream_t stream) {
  const float* vid0 = (const float*)d_in[0];
  const float* vid1 = (const float*)d_in[1];
  // d_in[2] = flows: unused by the reference.
  float* out = (float*)d_out;

  // Workspace layout:
  //   dists : QC*SC fp32  = 1.33 MB
  //   topk  : QC*KK int32 = 48 KB
  //   v0t   : TT*HH*WW*CC fp32 = 28.3 MB
  //   v1t   : 28.3 MB
  char* ws = (char*)d_ws;
  float* dists = (float*)ws;
  size_t off = (size_t)QC * SC * sizeof(float);
  int* topk = (int*)(ws + off);
  off += (size_t)QC * KK * sizeof(int);
  off = (off + 255) & ~(size_t)255;
  float* v0t = (float*)(ws + off);
  size_t vbytes = (size_t)TT * HWW * CC * sizeof(float);
  float* v1t = (float*)(ws + off + vbytes);

  transpose_tchw_thwc<<<dim3(TT * HH * (WW / 64), 2), 256, 0, stream>>>(
      vid0, vid1, v0t, v1t);
  coarse_fma_kernel<<<QC, 256, 0, stream>>>(v0t, v1t, dists);
  topk_kernel<<<(QC * 64 + 255) / 256, 256, 0, stream>>>(dists, topk);
  refine_kernel<<<QF, 448, 0, stream>>>(v0t, v1t, topk, out);
}

// Round 4
// 275.141 us; speedup vs baseline: 1.1116x; 1.1116x over previous
//
#include <hip/hip_runtime.h>
#include <math.h>

// Problem constants (B=1, NHEADS=1)
#define TT   3
#define CC   64
#define HH   192
#define WW   192
#define HWW  (HH*WW)       // 36864
#define NHC  24            // H / STRIDE0_A
#define NWC  24
#define QC   1728          // T*NHC*NWC
#define SC   192           // st*WS*WS = 3*8*8
#define NPIX 49            // PS*PS
#define KK   7
#define NHF  48            // H / STRIDE0
#define NWF  48
#define QF   6912          // T*NHF*NWF

__device__ __forceinline__ int reflect(int i, int L) {
  i = i < 0 ? -i : i;
  return (i >= L) ? (2 * (L - 1) - i) : i;
}

// ---------------------------------------------------------------------------
// (T,C,H,W) -> (T,H,W,C) fp32 transpose, 64x64 (c,x) tiles per (t,y).
// ---------------------------------------------------------------------------
__global__ void transpose_tchw_thwc(const float* __restrict__ in0,
                                    const float* __restrict__ in1,
                                    float* __restrict__ out0,
                                    float* __restrict__ out1) {
  const float* in = blockIdx.y ? in1 : in0;
  float* out = blockIdx.y ? out1 : out0;
  int b = blockIdx.x;              // 0 .. T*H*(W/64)-1
  int x0 = (b % 3) * 64;
  int ty = b / 3;                  // t*H + y
  int t = ty / HH, y = ty % HH;

  __shared__ float tile[64][65];   // +1 pad
  int lx = threadIdx.x & 63;
  int lc = threadIdx.x >> 6;       // 0..3

  const float* src = in + (size_t)t * CC * HWW + (size_t)y * WW + x0;
#pragma unroll
  for (int i = 0; i < 16; ++i) {
    int c = lc + i * 4;
    tile[c][lx] = src[(size_t)c * HWW + lx];
  }
  __syncthreads();
  float* dst = out + ((size_t)(t * HH + y) * WW + x0) * CC;
#pragma unroll
  for (int i = 0; i < 16; ++i) {
    int x = lc + i * 4;
    dst[(size_t)x * CC + lx] = tile[lx][x];   // coalesced along c
  }
}

// ---------------------------------------------------------------------------
// Coarse dists, bit-exact vs the XLA chain:
//   w(s,p) = serial ascending-c FMA chain, single fp32 acc (c 0..63, carried
//            in a register across the two c-halves).
//   dist  = 49 sequential fp32 adds, p ascending (lax.scan order).
//
// v5 = v3's proven body (VGPR 68, zero scratch) + ONE change:
//  - wbuf ALIASED into region4 (never live simultaneously; one extra barrier
//    per ct) -> LDS 50176 -> 37632 B -> 4 blocks/CU (was 3).
// v4's register-prefetch is REVERTED: its conditionally-defined arrays
// (if (sdst[j]>=0) rbuf[j]=...) were demoted to scratch (WRITE_SIZE 1.3MB ->
// 243MB, rule #20 variant: conditional defs block array promotion).
// ---------------------------------------------------------------------------
__global__ __launch_bounds__(256, 4) void coarse_fma_kernel(
    const float* __restrict__ v0, const float* __restrict__ v1,
    float* __restrict__ dists) {
  int bid = blockIdx.x;
  int q = (bid & 7) * (QC / 8) + (bid >> 3);   // XCD swizzle, bijective
  int qt = q / (NHC * NWC);
  int r = q % (NHC * NWC);
  int qh = (r / NWC) * 8;
  int qw = (r % NWC) * 8;

  __shared__ float4 region4[8 * 196];   // [c4h][px] 25088 B; wbuf aliases
  __shared__ float4 qbuf4[16 * 49];     // [c4][p]   12544 B  (total 37632)
  float* wbuf = (float*)region4;        // [s][p] 12544 B, after compute sync

  int tid = threadIdx.x;
  int s = tid & 63;
  int w = tid >> 6;                     // wave id 0..3
  int oi = s >> 3, oj = s & 7;

  // Per-thread region byte offsets, ct-independent. p = w + 4*i.
  int pxb[13];
#pragma unroll
  for (int i = 0; i < 13; ++i) {
    int p = w + 4 * i;
    if (p > 48) p = 48;                 // clamped slot is never used
    pxb[i] = ((oi + p / 7) * 14 + (oj + p % 7)) * 16;
  }

  // Stage query patch [c4][p] float4 (write chunk-slots even over lanes).
  {
    const float* b0 = v0 + (size_t)qt * HWW * CC;
    for (int idx = tid; idx < 896; idx += 256) {
      int p = (idx & 7) | ((idx >> 7) << 3);
      int c4 = (idx >> 3) & 15;
      if (p < 49) {
        int ry = reflect(qh + p / 7 - 3, HH);
        int rx = reflect(qw + p % 7 - 3, WW);
        qbuf4[c4 * 49 + p] = *reinterpret_cast<const float4*>(
            b0 + ((size_t)ry * WW + rx) * CC + c4 * 4);
      }
    }
  }

  for (int ct = 0; ct < 3; ++ct) {
    const float* b1 = v1 + (size_t)ct * HWW * CC;
    float acc[13];
#pragma unroll
    for (int i = 0; i < 13; ++i) acc[i] = 0.f;

#pragma unroll
    for (int h = 0; h < 2; ++h) {
      __syncthreads();  // prior region4/wbuf readers done
      // Stage c-half h of the 14x14 window: 8 c4 x 196 px float4.
      // Lane mapping: px in low 3 lane bits -> write chunk-slots even.
      for (int idx = tid; idx < 1600; idx += 256) {
        int px = (idx & 7) | ((idx >> 6) << 3);
        int c4h = (idx >> 3) & 7;
        if (px < 196) {
          int ry = reflect(qh - 7 + px / 14, HH);
          int rx = reflect(qw - 7 + px % 14, WW);
          region4[c4h * 196 + px] = *reinterpret_cast<const float4*>(
              b1 + ((size_t)ry * WW + rx) * CC + (h * 8 + c4h) * 4);
        }
      }
      __syncthreads();

      // Continue each dot's serial chain: c = 32h .. 32h+31, ascending,
      // single register accumulator per (s,p) — bit-identical ordering.
#pragma unroll
      for (int i = 0; i < 13; ++i) {
        if (i < 12 || w == 0) {          // p = w+48 exists only for wave 0
          int p = w + 4 * i;             // wave-uniform -> qbuf read = bcast
          const char* rbase = reinterpret_cast<const char*>(region4) + pxb[i];
#pragma unroll
          for (int c4h = 0; c4h < 8; ++c4h) {
            float4 a = qbuf4[(h * 8 + c4h) * 49 + p];
            float4 b = *reinterpret_cast<const float4*>(rbase + c4h * 3136);
            acc[i] = fmaf(a.x, b.x, acc[i]);   // ascending c, fused
            acc[i] = fmaf(a.y, b.y, acc[i]);
            acc[i] = fmaf(a.z, b.z, acc[i]);
            acc[i] = fmaf(a.w, b.w, acc[i]);
          }
        }
      }
    }

    __syncthreads();     // all region4 readers done -> wbuf alias writable
    // Publish dots; reduce over p in scan order.
#pragma unroll
    for (int i = 0; i < 13; ++i) {
      if (i < 12 || w == 0) wbuf[s * 49 + (w + 4 * i)] = acc[i];
    }
    __syncthreads();
    if (tid < 64) {
      float a = 0.f;
      const float* wr = wbuf + tid * 49;
      for (int p = 0; p < NPIX; ++p)
        a = __fadd_rn(a, wr[p]);         // scan order, fp32
      dists[(size_t)q * SC + ct * 64 + tid] = a;
    }
    // Next ct's first __syncthreads fences the reduce before region reuse.
  }
}

// ---------------------------------------------------------------------------
// Top-K (K=7): one WAVE per query. Lane owns candidates {lane, lane+64,
// lane+128}. Bit-exact vs serial strict-'>' ascending scan (ties -> lowest
// index via the cross-lane index tie-break).
// ---------------------------------------------------------------------------
__global__ __launch_bounds__(256) void topk_kernel(
    const float* __restrict__ dists, int* __restrict__ topk) {
  int q = blockIdx.x * 4 + (threadIdx.x >> 6);
  if (q >= QC) return;
  int lane = threadIdx.x & 63;
  const float* d = dists + (size_t)q * SC;
  float v[3] = {d[lane], d[lane + 64], d[lane + 128]};
  int tk = 0;                            // taken bitmask (per-lane, 3 bits)
#pragma unroll
  for (int k = 0; k < KK; ++k) {
    float bv = -INFINITY;
    int bi = 0x7fffffff;
#pragma unroll
    for (int j = 0; j < 3; ++j) {
      if (!((tk >> j) & 1) && v[j] > bv) { bv = v[j]; bi = lane + j * 64; }
    }
#pragma unroll
    for (int off = 32; off > 0; off >>= 1) {
      float ov = __shfl_xor(bv, off, 64);
      int oi = __shfl_xor(bi, off, 64);
      if (ov > bv || (ov == bv && oi < bi)) { bv = ov; bi = oi; }
    }
    if ((bi & 63) == lane) tk |= 1 << (bi >> 6);
    if (lane == 0) topk[q * KK + k] = bi;
  }
}

// ---------------------------------------------------------------------------
// Refine. One block per fine query, 448 threads = 7 waves, one wave per
// candidate k. Query patch staged once in LDS; candidate loads batched
// 7-wide for ILP. XCD swizzle for L2 locality.
// ---------------------------------------------------------------------------
__global__ __launch_bounds__(448, 7) void refine_kernel(
    const float* __restrict__ v0, const float* __restrict__ v1,
    const int* __restrict__ topk, float* __restrict__ out) {
  int bid = blockIdx.x;
  int f = (bid & 7) * (QF / 8) + (bid >> 3);   // XCD swizzle, bijective
  int ft = f / (NHF * NWF);
  int r = f % (NHF * NWF);
  int fi = r / NWF, fj = r % NWF;
  int fh = fi * 4, fw = fj * 4;
  int ci = fi >> 1, cj = fj >> 1;     // clip is a no-op here
  int dh = (fi & 1) * 4, dw = (fj & 1) * 4;
  int qlin = ft * (NHC * NWC) + ci * NWC + cj;

  int tid = threadIdx.x;
  int lane = tid & 63;
  int k = tid >> 6;                   // wave id == candidate id, 0..6

  __shared__ float qs[NPIX * CC];     // [p][c], 12544 B

  {
    const float* b0 = v0 + (size_t)ft * HWW * CC;
#pragma unroll
    for (int i = 0; i < 7; ++i) {     // 7 * 448 = 3136 = NPIX*CC exactly
      int idx = tid + i * 448;
      int p = idx >> 6, c = idx & 63;
      int ry = reflect(fh + p / 7 - 3, HH);
      int rx = reflect(fw + p % 7 - 3, WW);
      qs[idx] = b0[((size_t)ry * WW + rx) * CC + c];
    }
  }
  __syncthreads();

  int it, ih, iw;
  if (k == 0) {
    it = ft; ih = fh; iw = fw;
  } else {
    int s = topk[qlin * KK + k];
    int ti = s >> 6;                  // ct index (t0 == 0 always)
    int oi = (s >> 3) & 7, oj = s & 7;
    it = ti;
    ih = reflect(ci * 8 + oi - 4 + dh, HH);
    iw = reflect(cj * 8 + oj - 4 + dw, WW);
  }

  const float* b1 = v1 + (size_t)it * HWW * CC;
  float acc = 0.f;
#pragma unroll
  for (int pr = 0; pr < 7; ++pr) {
    int ry = reflect(ih + pr - 3, HH);
    const float* rowp = b1 + (size_t)ry * WW * CC + lane;
    float vals[7];
#pragma unroll
    for (int pc = 0; pc < 7; ++pc) {
      int rx = reflect(iw + pc - 3, WW);
      vals[pc] = rowp[(size_t)rx * CC];       // 7 independent loads in flight
    }
#pragma unroll
    for (int pc = 0; pc < 7; ++pc)
      acc = fmaf(qs[(pr * 7 + pc) * CC + lane], vals[pc], acc);
  }
#pragma unroll
  for (int off = 32; off > 0; off >>= 1)
    acc += __shfl_xor(acc, off, 64);
  if (lane == 0) {
    float* dout = out;                      // [0, QF*KK)
    float* iout = out + (size_t)QF * KK;    // [QF*KK, QF*KK*4)
    dout[(size_t)f * KK + k] = acc;
    float* ip = iout + ((size_t)f * KK + k) * 3;
    ip[0] = (float)it;
    ip[1] = (float)ih;
    ip[2] = (float)iw;
  }
}

// ---------------------------------------------------------------------------
extern "C" void kernel_launch(void* const* d_in, const int* in_sizes, int n_in,
                              void* d_out, int out_size, void* d_ws,
                              size_t ws_size, hipStream_t stream) {
  const float* vid0 = (const float*)d_in[0];
  const float* vid1 = (const float*)d_in[1];
  // d_in[2] = flows: unused by the reference.
  float* out = (float*)d_out;

  // Workspace layout:
  //   dists : QC*SC fp32  = 1.33 MB
  //   topk  : QC*KK int32 = 48 KB
  //   v0t   : TT*HH*WW*CC fp32 = 28.3 MB
  //   v1t   : 28.3 MB
  char* ws = (char*)d_ws;
  float* dists = (float*)ws;
  size_t off = (size_t)QC * SC * sizeof(float);
  int* topk = (int*)(ws + off);
  off += (size_t)QC * KK * sizeof(int);
  off = (off + 255) & ~(size_t)255;
  float* v0t = (float*)(ws + off);
  size_t vbytes = (size_t)TT * HWW * CC * sizeof(float);
  float* v1t = (float*)(ws + off + vbytes);

  transpose_tchw_thwc<<<dim3(TT * HH * (WW / 64), 2), 256, 0, stream>>>(
      vid0, vid1, v0t, v1t);
  coarse_fma_kernel<<<QC, 256, 0, stream>>>(v0t, v1t, dists);
  topk_kernel<<<(QC * 64 + 255) / 256, 256, 0, stream>>>(dists, topk);
  refine_kernel<<<QF, 448, 0, stream>>>(v0t, v1t, topk, out);
}